// Round 7
// baseline (270.828 us; speedup 1.0000x reference)
//
#include <hip/hip_runtime.h>

// WaveletParsingLayer: per-row stable stream compaction.
// x3[B,C,L] -> out[B,C,KEEP], dropping elements == FILLER (10.1f), order-preserving.
// x1, x2 unused.
//
// R7: 3-kernel pipeline, no redundant reads (R6's 98 MB over-fetch removed),
// no scattered global stores (R5-pass2's limiter), no serial barrier chain
// (R2/R4's limiter):
//   K1 count_segs : 8192 blocks, quarter-row each, writes 64 per-seg survivor
//                   counts per row (512 KB). No LDS, no barriers.
//   K2 prefix_rows: 2048 x 64-thread blocks, per-row exclusive prefix via
//                   __shfl_up. ~1 MB traffic.
//   K3 emit       : 8192 blocks, re-read own quarter (LLC-hot from K1),
//                   re-ballot lane positions + precomputed seg bases,
//                   16 KB LDS stage, contiguous coalesced stores.
// Element order: idx = q*4096 + c*1024 + w*256 + lane*4 + j -> seg = q*16+c*4+w.

#define FILLER_VAL 10.1f
constexpr int L_LEN    = 16384;
constexpr int KEEP_LEN = 12288;
constexpr int BLOCK    = 256;            // 4 waves of 64
constexpr int QELEM    = 4096;           // elements per block (quarter row)
constexpr int QCH      = 4;              // 1024-elem chunks per quarter
constexpr int NSEG     = 64;             // segments per row (4 q * 4 c * 4 w)

// ---------------- K1: per-segment survivor counts ---------------------------
__global__ __launch_bounds__(BLOCK) void count_segs(
    const float* __restrict__ x3, int* __restrict__ cnt)
{
    const int bid = blockIdx.x;
    const int row = bid >> 2;
    const int q   = bid & 3;
    const float* __restrict__ in = x3 + (size_t)row * L_LEN + q * QELEM;

    const int tid  = threadIdx.x;
    const int lane = tid & 63;
    const int wid  = tid >> 6;

    #pragma unroll
    for (int c = 0; c < QCH; ++c) {
        float4 v = *reinterpret_cast<const float4*>(in + c * (BLOCK * 4) + tid * 4);
        unsigned long long m0 = __ballot(v.x != FILLER_VAL);
        unsigned long long m1 = __ballot(v.y != FILLER_VAL);
        unsigned long long m2 = __ballot(v.z != FILLER_VAL);
        unsigned long long m3 = __ballot(v.w != FILLER_VAL);
        if (lane == 0)
            cnt[row * NSEG + q * 16 + c * 4 + wid] =
                __popcll(m0) + __popcll(m1) + __popcll(m2) + __popcll(m3);
    }
}

// ---------------- K2: per-row exclusive prefix over 64 seg counts -----------
__global__ __launch_bounds__(64) void prefix_rows(
    const int* __restrict__ cnt, int* __restrict__ base)
{
    const int row  = blockIdx.x;
    const int lane = threadIdx.x;

    const int own = cnt[row * NSEG + lane];
    int x = own;
    #pragma unroll
    for (int d = 1; d < 64; d <<= 1) {
        int y = __shfl_up(x, d);
        if (lane >= d) x += y;
    }
    base[row * NSEG + lane] = x - own;   // exclusive prefix
}

// ---------------- K3: staged emit with coalesced stores ---------------------
__global__ __launch_bounds__(BLOCK) void emit_quarters(
    const float* __restrict__ x3, const int* __restrict__ base,
    float* __restrict__ out)
{
    const int bid = blockIdx.x;
    const int row = bid >> 2;
    const int q   = bid & 3;

    const float* __restrict__ in = x3 + (size_t)row * L_LEN + q * QELEM;
    float* __restrict__ o = out + (size_t)row * KEEP_LEN;
    const int* __restrict__ rb = base + row * NSEG;

    const int tid  = threadIdx.x;
    const int lane = tid & 63;
    const int wid  = tid >> 6;
    const unsigned long long lt = (1ULL << lane) - 1ULL;

    __shared__ float stage[QELEM];   // 16 KB

    const int blockbase = rb[q * 16];

    #pragma unroll
    for (int c = 0; c < QCH; ++c) {
        float4 v = *reinterpret_cast<const float4*>(in + c * (BLOCK * 4) + tid * 4);
        unsigned long long m0 = __ballot(v.x != FILLER_VAL);
        unsigned long long m1 = __ballot(v.y != FILLER_VAL);
        unsigned long long m2 = __ballot(v.z != FILLER_VAL);
        unsigned long long m3 = __ballot(v.w != FILLER_VAL);
        const int before = __popcll(m0 & lt) + __popcll(m1 & lt)
                         + __popcll(m2 & lt) + __popcll(m3 & lt);

        int pos = rb[q * 16 + c * 4 + wid] - blockbase + before;

        if (v.x != FILLER_VAL) { if (pos >= 0 && pos < QELEM) stage[pos] = v.x; ++pos; }
        if (v.y != FILLER_VAL) { if (pos >= 0 && pos < QELEM) stage[pos] = v.y; ++pos; }
        if (v.z != FILLER_VAL) { if (pos >= 0 && pos < QELEM) stage[pos] = v.z; ++pos; }
        if (v.w != FILLER_VAL) { if (pos >= 0 && pos < QELEM) stage[pos] = v.w; ++pos; }
    }
    __syncthreads();

    // Survivors in this quarter = next quarter's base - mine (row total = KEEP).
    int cnt = ((q == 3) ? KEEP_LEN : rb[q * 16 + 16]) - blockbase;
    if (cnt > QELEM) cnt = QELEM;                       // safety
    if (blockbase + cnt > KEEP_LEN) cnt = KEEP_LEN - blockbase;

    for (int i = tid; i < cnt; i += BLOCK)
        o[blockbase + i] = stage[i];
}

extern "C" void kernel_launch(void* const* d_in, const int* in_sizes, int n_in,
                              void* d_out, int out_size, void* d_ws, size_t ws_size,
                              hipStream_t stream)
{
    // in order: x1 [B,C,4096] f32 (unused), x2 [B,C,4096] f32 (unused),
    //           x3 [B,C,L] f32, keep_len (scalar int, value 12288)
    const float* x3 = (const float*)d_in[2];
    float* out = (float*)d_out;

    const int rows = in_sizes[2] / L_LEN;   // B*C = 2048

    int* cnt  = (int*)d_ws;                       // rows*64 ints = 512 KB
    int* bas  = cnt + (size_t)rows * NSEG;        // rows*64 ints = 512 KB

    count_segs  <<<rows * 4, BLOCK, 0, stream>>>(x3, cnt);
    prefix_rows <<<rows,     64,    0, stream>>>(cnt, bas);
    emit_quarters<<<rows * 4, BLOCK, 0, stream>>>(x3, bas, out);
}